// Round 1
// baseline (1163.923 us; speedup 1.0000x reference)
//
#include <hip/hip_runtime.h>
#include <hip/hip_bf16.h>

#define N_NODES 100000
#define D 128
#define EPT 250000
#define NT 7
#define NSEG (NT * N_NODES)   // 700000 segments (type, node)
#define TOTE (NT * EPT)       // 1750000 edges

#define SCAN_B 256
#define SCAN_IPT 4
#define SCAN_CHUNK (SCAN_B * SCAN_IPT)                    // 1024
#define SCAN_NBLK ((NSEG + SCAN_CHUNK - 1) / SCAN_CHUNK)  // 684

// ---------------- CSR build ----------------

__global__ void count_edges(const int* __restrict__ e, int* __restrict__ cnt, int t) {
    int i = blockIdx.x * blockDim.x + threadIdx.x;
    if (i < EPT) {
        int dst = e[EPT + i];
        atomicAdd(&cnt[t * N_NODES + dst], 1);
    }
}

__global__ void scan_partials(const int* __restrict__ cnt, int* __restrict__ partials) {
    __shared__ int wsum[4];
    int tid = threadIdx.x;
    int base = blockIdx.x * SCAN_CHUNK + tid * SCAN_IPT;
    int s = 0;
#pragma unroll
    for (int j = 0; j < SCAN_IPT; ++j) {
        int idx = base + j;
        if (idx < NSEG) s += cnt[idx];
    }
    for (int off = 32; off > 0; off >>= 1) s += __shfl_down(s, off);
    if ((tid & 63) == 0) wsum[tid >> 6] = s;
    __syncthreads();
    if (tid == 0) partials[blockIdx.x] = wsum[0] + wsum[1] + wsum[2] + wsum[3];
}

__global__ void scan_block(int* partials, int nb) {
    __shared__ int sh[1024];
    int tid = threadIdx.x;
    int v = (tid < nb) ? partials[tid] : 0;
    sh[tid] = v;
    __syncthreads();
    for (int off = 1; off < 1024; off <<= 1) {
        int a = (tid >= off) ? sh[tid - off] : 0;
        __syncthreads();
        sh[tid] += a;
        __syncthreads();
    }
    if (tid < nb) partials[tid] = sh[tid] - v;  // exclusive
}

__global__ void scan_write(const int* __restrict__ cnt, const int* __restrict__ partials,
                           int* __restrict__ scanbuf) {
    __shared__ int wsum[4];
    int tid = threadIdx.x;
    int base = blockIdx.x * SCAN_CHUNK + tid * SCAN_IPT;
    int v[SCAN_IPT];
    int tsum = 0;
#pragma unroll
    for (int j = 0; j < SCAN_IPT; ++j) {
        int idx = base + j;
        v[j] = (idx < NSEG) ? cnt[idx] : 0;
        tsum += v[j];
    }
    int lane = tid & 63, wid = tid >> 6;
    int inc = tsum;
    for (int d = 1; d < 64; d <<= 1) {
        int o = __shfl_up(inc, d);
        if (lane >= d) inc += o;
    }
    if (lane == 63) wsum[wid] = inc;
    __syncthreads();
    int woff = 0;
    for (int w = 0; w < wid; ++w) woff += wsum[w];
    int exc = woff + inc - tsum + partials[blockIdx.x];
#pragma unroll
    for (int j = 0; j < SCAN_IPT; ++j) {
        int idx = base + j;
        if (idx < NSEG) scanbuf[idx] = exc;
        exc += v[j];
    }
}

__global__ void copy_int(const int* __restrict__ src, int* __restrict__ dst, int n) {
    int i = blockIdx.x * blockDim.x + threadIdx.x;
    if (i < n) dst[i] = src[i];
}

__global__ void fill_edges(const int* __restrict__ e, int* __restrict__ cursor,
                           int* __restrict__ esrc, int t) {
    int i = blockIdx.x * blockDim.x + threadIdx.x;
    if (i < EPT) {
        int src = e[i];
        int dst = e[EPT + i];
        int pos = atomicAdd(&cursor[t * N_NODES + dst], 1);
        esrc[pos] = src;
    }
}

// ---------------- aggregation: A_p[n] = mean over segment of x[src] ----------------
// pass < 7: per-type segment (pass, n). pass == 7: union of all 7 segments (global pass).

__global__ __launch_bounds__(256) void aggregate(const float* __restrict__ x,
                                                 const int* __restrict__ scanbuf,
                                                 const int* __restrict__ cnt,
                                                 const int* __restrict__ esrc,
                                                 float* __restrict__ A, int pass) {
    int tid = threadIdx.x;
    int g = tid >> 5, lane = tid & 31;
    int n = blockIdx.x * 8 + g;
    if (n >= N_NODES) return;
    const float4* x4 = (const float4*)x;
    float4 acc = make_float4(0.f, 0.f, 0.f, 0.f);
    int total = 0;
    int t0 = (pass < NT) ? pass : 0;
    int t1 = (pass < NT) ? pass + 1 : NT;
    for (int t = t0; t < t1; ++t) {
        int seg = t * N_NODES + n;
        int s = scanbuf[seg];
        int c = cnt[seg];
        total += c;
        for (int j = 0; j < c; ++j) {
            int src = esrc[s + j];
            float4 xv = x4[src * 32 + lane];
            acc.x += xv.x; acc.y += xv.y; acc.z += xv.z; acc.w += xv.w;
        }
    }
    float inv = 1.0f / (float)((total > 0) ? total : 1);
    ((float4*)A)[n * 32 + lane] = make_float4(acc.x * inv, acc.y * inv, acc.z * inv, acc.w * inv);
}

// ---------------- per-pass GEMM: out += (A @ W[pass]) / 8 ----------------
// block = 512 threads, 128 nodes; W (64KB) + A tile (64KB) in LDS.

__global__ __launch_bounds__(512) void gemm_pass(const float* __restrict__ A,
                                                 const float* __restrict__ W8,
                                                 float* __restrict__ out, int pass) {
    __shared__ float Wl[D * D];       // 64 KB
    __shared__ float Al[128 * D];     // 64 KB
    int tid = threadIdx.x;
    const float4* Wg4 = (const float4*)(W8 + pass * D * D);
    float4* Wl4 = (float4*)Wl;
#pragma unroll
    for (int s = 0; s < 8; ++s) Wl4[s * 512 + tid] = Wg4[s * 512 + tid];  // 4096 float4

    int n0 = blockIdx.x * 128;
    const float4* A4 = (const float4*)A;
    float4* Al4 = (float4*)Al;
#pragma unroll
    for (int s = 0; s < 8; ++s) {
        int idx = s * 512 + tid;       // 0..4095 ; node-local = idx>>5, f4col = idx&31
        int nl = idx >> 5;
        int n = n0 + nl;
        Al4[idx] = (n < N_NODES) ? A4[n * 32 + (idx & 31)] : make_float4(0.f, 0.f, 0.f, 0.f);
    }
    __syncthreads();

    int c = tid & 31;   // f4 column group: cols c*4..c*4+3
    int r = tid >> 5;   // node group: nodes r*8..r*8+7
    float acc[8][4];
#pragma unroll
    for (int i = 0; i < 8; ++i)
        for (int q = 0; q < 4; ++q) acc[i][q] = 0.f;

#pragma unroll 4
    for (int k = 0; k < D; ++k) {
        float4 w = Wl4[k * 32 + c];
#pragma unroll
        for (int i = 0; i < 8; ++i) {
            float a = Al[(r * 8 + i) * D + k];
            acc[i][0] += a * w.x;
            acc[i][1] += a * w.y;
            acc[i][2] += a * w.z;
            acc[i][3] += a * w.w;
        }
    }

#pragma unroll
    for (int i = 0; i < 8; ++i) {
        int n = n0 + r * 8 + i;
        if (n < N_NODES) {
            float4* o = (float4*)out + n * 32 + c;
            float4 cur = *o;
            cur.x += acc[i][0] * 0.125f;
            cur.y += acc[i][1] * 0.125f;
            cur.z += acc[i][2] * 0.125f;
            cur.w += acc[i][3] * 0.125f;
            *o = cur;
        }
    }
}

// ---------------- launch ----------------

extern "C" void kernel_launch(void* const* d_in, const int* in_sizes, int n_in,
                              void* d_out, int out_size, void* d_ws, size_t ws_size,
                              hipStream_t stream) {
    const float* x = (const float*)d_in[0];
    const float* W = (const float*)d_in[1];
    const int* e[NT];
    for (int t = 0; t < NT; ++t) e[t] = (const int*)d_in[2 + t];
    float* out = (float*)d_out;

    char* ws = (char*)d_ws;
    int* cnt      = (int*)(ws + 0);                    // 2.8 MB
    int* scanbuf  = (int*)(ws + 2800000);              // 2.8 MB
    int* cursor   = (int*)(ws + 5600000);              // 2.8 MB
    int* partials = (int*)(ws + 8400000);              // 4 KB
    int* esrc     = (int*)(ws + 8404096);              // 7 MB
    float* A      = (float*)(ws + 15404096);           // 51.2 MB

    hipMemsetAsync(cnt, 0, NSEG * sizeof(int), stream);
    hipMemsetAsync(out, 0, (size_t)out_size * sizeof(float), stream);

    int ebl = (EPT + 255) / 256;
    for (int t = 0; t < NT; ++t)
        count_edges<<<ebl, 256, 0, stream>>>(e[t], cnt, t);

    scan_partials<<<SCAN_NBLK, SCAN_B, 0, stream>>>(cnt, partials);
    scan_block<<<1, 1024, 0, stream>>>(partials, SCAN_NBLK);
    scan_write<<<SCAN_NBLK, SCAN_B, 0, stream>>>(cnt, partials, scanbuf);

    copy_int<<<(NSEG + 255) / 256, 256, 0, stream>>>(scanbuf, cursor, NSEG);
    for (int t = 0; t < NT; ++t)
        fill_edges<<<ebl, 256, 0, stream>>>(e[t], cursor, esrc, t);

    int agg_grid = (N_NODES + 7) / 8;
    int gemm_grid = (N_NODES + 127) / 128;
    for (int p = 0; p < NT + 1; ++p) {
        aggregate<<<agg_grid, 256, 0, stream>>>(x, scanbuf, cnt, esrc, A, p);
        gemm_pass<<<gemm_grid, 512, 0, stream>>>(A, W, out, p);
    }
}

// Round 2
// 585.272 us; speedup vs baseline: 1.9887x; 1.9887x over previous
//
#include <hip/hip_runtime.h>
#include <hip/hip_bf16.h>

#define N_NODES 100000
#define D 128
#define EPT 250000
#define NT 7
#define NSEG (NT * N_NODES)   // 700000
#define TOTE (NT * EPT)       // 1750000
#define MPAD 100352           // multiple of 128 >= N_NODES

#define SCAN_B 256
#define SCAN_IPT 4
#define SCAN_CHUNK (SCAN_B * SCAN_IPT)                    // 1024
#define SCAN_NBLK ((NSEG + SCAN_CHUNK - 1) / SCAN_CHUNK)  // 684

typedef __attribute__((ext_vector_type(8))) short bf16x8;
typedef __attribute__((ext_vector_type(4))) float f32x4;

__device__ inline float b2f(unsigned int u16) {
    union { unsigned int i; float f; } v; v.i = u16 << 16; return v.f;
}
__device__ inline unsigned short f2b(float f) {
    union { float f; unsigned int i; } v; v.f = f;
    unsigned int r = v.i + 0x7fffu + ((v.i >> 16) & 1u);
    return (unsigned short)(r >> 16);
}
__device__ inline unsigned int pack2(float a, float b) {
    return (unsigned int)f2b(a) | ((unsigned int)f2b(b) << 16);
}

struct EPtrs { const int* e[NT]; };

// ---------------- dtype conversion ----------------

__global__ void convert_x(const float4* __restrict__ x, uint2* __restrict__ xb, int n4) {
    int i = blockIdx.x * blockDim.x + threadIdx.x;
    if (i < n4) {
        float4 v = x[i];
        xb[i] = make_uint2(pack2(v.x, v.y), pack2(v.z, v.w));
    }
}

// WbT[c][tk] = W[tk][c]   (tk = t*128+k, 1024 of them; c = 0..127)
__global__ void convert_w(const float* __restrict__ W, unsigned short* __restrict__ WbT) {
    int i = blockIdx.x * blockDim.x + threadIdx.x;  // 131072
    int c = i >> 10, tk = i & 1023;
    WbT[i] = f2b(W[tk * 128 + c]);
}

// ---------------- CSR build ----------------

__global__ void count_all(EPtrs ep, int* __restrict__ cnt) {
    int i = blockIdx.x * blockDim.x + threadIdx.x;
    int t = blockIdx.y;
    if (i < EPT) {
        int dst = ep.e[t][EPT + i];
        atomicAdd(&cnt[t * N_NODES + dst], 1);
    }
}

__global__ void scan_partials(const int* __restrict__ cnt, int* __restrict__ partials) {
    __shared__ int wsum[4];
    int tid = threadIdx.x;
    int base = blockIdx.x * SCAN_CHUNK + tid * SCAN_IPT;
    int s = 0;
#pragma unroll
    for (int j = 0; j < SCAN_IPT; ++j) {
        int idx = base + j;
        if (idx < NSEG) s += cnt[idx];
    }
    for (int off = 32; off > 0; off >>= 1) s += __shfl_down(s, off);
    if ((tid & 63) == 0) wsum[tid >> 6] = s;
    __syncthreads();
    if (tid == 0) partials[blockIdx.x] = wsum[0] + wsum[1] + wsum[2] + wsum[3];
}

__global__ void scan_block(int* partials, int nb) {
    __shared__ int sh[1024];
    int tid = threadIdx.x;
    int v = (tid < nb) ? partials[tid] : 0;
    sh[tid] = v;
    __syncthreads();
    for (int off = 1; off < 1024; off <<= 1) {
        int a = (tid >= off) ? sh[tid - off] : 0;
        __syncthreads();
        sh[tid] += a;
        __syncthreads();
    }
    if (tid < nb) partials[tid] = sh[tid] - v;  // exclusive
}

__global__ void scan_write(const int* __restrict__ cnt, const int* __restrict__ partials,
                           int* __restrict__ scanbuf) {
    __shared__ int wsum[4];
    int tid = threadIdx.x;
    int base = blockIdx.x * SCAN_CHUNK + tid * SCAN_IPT;
    int v[SCAN_IPT];
    int tsum = 0;
#pragma unroll
    for (int j = 0; j < SCAN_IPT; ++j) {
        int idx = base + j;
        v[j] = (idx < NSEG) ? cnt[idx] : 0;
        tsum += v[j];
    }
    int lane = tid & 63, wid = tid >> 6;
    int inc = tsum;
    for (int d = 1; d < 64; d <<= 1) {
        int o = __shfl_up(inc, d);
        if (lane >= d) inc += o;
    }
    if (lane == 63) wsum[wid] = inc;
    __syncthreads();
    int woff = 0;
    for (int w = 0; w < wid; ++w) woff += wsum[w];
    int exc = woff + inc - tsum + partials[blockIdx.x];
#pragma unroll
    for (int j = 0; j < SCAN_IPT; ++j) {
        int idx = base + j;
        if (idx < NSEG) scanbuf[idx] = exc;
        exc += v[j];
    }
}

__global__ void copy_int(const int* __restrict__ src, int* __restrict__ dst, int n) {
    int i = blockIdx.x * blockDim.x + threadIdx.x;
    if (i < n) dst[i] = src[i];
}

__global__ void fill_all(EPtrs ep, int* __restrict__ cursor, int* __restrict__ esrc) {
    int i = blockIdx.x * blockDim.x + threadIdx.x;
    int t = blockIdx.y;
    if (i < EPT) {
        int src = ep.e[t][i];
        int dst = ep.e[t][EPT + i];
        int pos = atomicAdd(&cursor[t * N_NODES + dst], 1);
        esrc[pos] = src;
    }
}

// ---------------- fused aggregation: all 7 per-type means + global mean ----------------
// one 64-lane wave per node; lane covers 2 columns; writes A8 row [8*128] bf16.

__global__ __launch_bounds__(256) void aggregate_all(const unsigned short* __restrict__ xb,
                                                     const int* __restrict__ scanbuf,
                                                     const int* __restrict__ cnt,
                                                     const int* __restrict__ esrc,
                                                     unsigned short* __restrict__ A8,
                                                     int base) {
    int tid = threadIdx.x;
    int w = tid >> 6, lane = tid & 63;
    int n = base + blockIdx.x * 4 + w;
    if (n >= N_NODES) return;

    const unsigned int* xr = (const unsigned int*)xb;  // pairs of bf16
    float a0[NT], a1[NT];
    int cc[NT];
    int total = 0;
#pragma unroll
    for (int t = 0; t < NT; ++t) {
        int seg = t * N_NODES + n;
        int s = scanbuf[seg];
        int c = cnt[seg];
        cc[t] = c;
        total += c;
        float s0 = 0.f, s1 = 0.f;
        for (int j = 0; j < c; ++j) {
            int src = esrc[s + j];
            unsigned int v = xr[(size_t)src * 64 + lane];
            s0 += b2f(v & 0xffffu);
            s1 += b2f(v >> 16);
        }
        a0[t] = s0; a1[t] = s1;
    }

    unsigned int* dst = (unsigned int*)A8 + (size_t)(n - base) * 512 + lane;
    float g0 = 0.f, g1 = 0.f;
#pragma unroll
    for (int t = 0; t < NT; ++t) {
        float inv = 1.0f / (float)(cc[t] > 0 ? cc[t] : 1);
        dst[t * 64] = pack2(a0[t] * inv, a1[t] * inv);
        g0 += a0[t]; g1 += a1[t];
    }
    float gi = 1.0f / (float)(total > 0 ? total : 1);
    dst[NT * 64] = pack2(g0 * gi, g1 * gi);
}

// ---------------- single MFMA GEMM: out = A8[rows,1024] @ Wflat[1024,128] / 8 ----------------
// block = 256 threads (4 waves); block tile 128 rows x 128 cols; wave tile 32x128.

__global__ __launch_bounds__(256) void gemm8(const unsigned short* __restrict__ A8,
                                             const unsigned short* __restrict__ WbT,
                                             float* __restrict__ out, int base) {
    int tid = threadIdx.x;
    int wv = tid >> 6, lane = tid & 63;
    int lr = lane & 15, lk = lane >> 4;
    int r0 = blockIdx.x * 128 + wv * 32;  // chunk-local row base for this wave

    f32x4 acc[2][8];
#pragma unroll
    for (int i = 0; i < 2; ++i)
#pragma unroll
        for (int j = 0; j < 8; ++j) acc[i][j] = (f32x4){0.f, 0.f, 0.f, 0.f};

    for (int k0 = 0; k0 < 1024; k0 += 32) {
        bf16x8 fa0 = *(const bf16x8*)(A8 + (size_t)(r0 + lr) * 1024 + k0 + lk * 8);
        bf16x8 fa1 = *(const bf16x8*)(A8 + (size_t)(r0 + 16 + lr) * 1024 + k0 + lk * 8);
#pragma unroll
        for (int tc = 0; tc < 8; ++tc) {
            bf16x8 fb = *(const bf16x8*)(WbT + (size_t)(tc * 16 + lr) * 1024 + k0 + lk * 8);
            acc[0][tc] = __builtin_amdgcn_mfma_f32_16x16x32_bf16(fa0, fb, acc[0][tc], 0, 0, 0);
            acc[1][tc] = __builtin_amdgcn_mfma_f32_16x16x32_bf16(fa1, fb, acc[1][tc], 0, 0, 0);
        }
    }

#pragma unroll
    for (int tr = 0; tr < 2; ++tr)
#pragma unroll
        for (int tc = 0; tc < 8; ++tc)
#pragma unroll
            for (int q = 0; q < 4; ++q) {
                int n = base + r0 + tr * 16 + lk * 4 + q;
                if (n < N_NODES)
                    out[(size_t)n * 128 + tc * 16 + lr] = acc[tr][tc][q] * 0.125f;
            }
}

// ---------------- launch ----------------

extern "C" void kernel_launch(void* const* d_in, const int* in_sizes, int n_in,
                              void* d_out, int out_size, void* d_ws, size_t ws_size,
                              hipStream_t stream) {
    const float* x = (const float*)d_in[0];
    const float* W = (const float*)d_in[1];
    EPtrs ep;
    for (int t = 0; t < NT; ++t) ep.e[t] = (const int*)d_in[2 + t];
    float* out = (float*)d_out;

    char* ws = (char*)d_ws;
    int* cnt            = (int*)(ws + 0);               // 2,800,000
    int* scanbuf        = (int*)(ws + 2800000);         // 2,800,000
    int* cursor         = (int*)(ws + 5600000);         // 2,800,000
    int* partials       = (int*)(ws + 8400000);         // 4,096
    unsigned short* WbT = (unsigned short*)(ws + 8404096);   // 262,144
    int* esrc           = (int*)(ws + 8666240);         // 7,000,000
    unsigned short* xb  = (unsigned short*)(ws + 15666240);  // 25,600,000
    unsigned short* A8  = (unsigned short*)(ws + 41266240);  // rest

    // adaptive chunk size for A8 (2048 B per node row)
    size_t avail = (ws_size > 41266240ULL) ? ws_size - 41266240ULL : 0;
    long long cr = (long long)(avail / 2048);
    cr = (cr / 128) * 128;
    if (cr < 128) cr = 128;
    if (cr > MPAD) cr = MPAD;

    hipMemsetAsync(cnt, 0, NSEG * sizeof(int), stream);

    convert_x<<<(N_NODES * D / 4 + 255) / 256, 256, 0, stream>>>((const float4*)x, (uint2*)xb, N_NODES * D / 4);
    convert_w<<<(1024 * 128 + 255) / 256, 256, 0, stream>>>(W, WbT);

    dim3 egrid((EPT + 255) / 256, NT);
    count_all<<<egrid, 256, 0, stream>>>(ep, cnt);

    scan_partials<<<SCAN_NBLK, SCAN_B, 0, stream>>>(cnt, partials);
    scan_block<<<1, 1024, 0, stream>>>(partials, SCAN_NBLK);
    scan_write<<<SCAN_NBLK, SCAN_B, 0, stream>>>(cnt, partials, scanbuf);

    copy_int<<<(NSEG + 255) / 256, 256, 0, stream>>>(scanbuf, cursor, NSEG);
    fill_all<<<egrid, 256, 0, stream>>>(ep, cursor, esrc);

    for (long long basell = 0; basell < N_NODES; basell += cr) {
        int base = (int)basell;
        long long rows = MPAD - basell < cr ? MPAD - basell : cr;  // multiple of 128
        int agg_blocks = (int)(rows / 4);
        int gemm_blocks = (int)(rows / 128);
        aggregate_all<<<agg_blocks, 256, 0, stream>>>(xb, scanbuf, cnt, esrc, A8, base);
        gemm8<<<gemm_blocks, 256, 0, stream>>>(A8, WbT, out, base);
    }
}